// Round 1
// baseline (30930.518 us; speedup 1.0000x reference)
//
#include <hip/hip_runtime.h>
#include <math.h>

// GraphWaveNet forward, f32 baseline.
// Activations layout: [b_local][c][t][n], n (=2048) innermost -> GCN einsum is a
// row-major GEMM (B*32*T x 2048)*(2048 x 2048).
// Batch processed in 2 chunks of 8 to keep workspace ~180 MB.
// skip telescopes: only last time step of each layer contributes.

#define NNODE 2048
#define NLAYER 8

// ---- workspace offsets (floats) ----
#define OFF_ADP  0UL                       // 2048*2048            = 4,194,304
#define OFF_SKIP 4194304UL                 // 16*256*2048          = 8,388,608
#define OFF_A    12582912UL                // 8*32*13*2048         = 6,815,744
#define OFF_B    19398656UL                // 8*32*13*2048         = 6,815,744
#define OFF_XG   26214400UL                // 8*32*12*2048         = 6,291,456
#define OFF_T1   32505856UL                // 6,291,456
#define OFF_T2   38797312UL                // 6,291,456
// total = 45,088,768 floats = 180,355,072 bytes
// h (16*512*2048 = 16,777,216) overlays XG..T2 (18,874,368) after the layer loops.

// ---------------- adp = softmax(relu(nv1 @ nv2), axis=1) ----------------
__global__ __launch_bounds__(256) void k_adp_mm(const float* __restrict__ nv1,
                                                const float* __restrict__ nv2,
                                                float* __restrict__ P) {
    int v = blockIdx.y;
    int w = blockIdx.x * 256 + threadIdx.x;
    float acc = 0.f;
#pragma unroll
    for (int k = 0; k < 10; ++k) acc += nv1[v * 10 + k] * nv2[k * NNODE + w];
    P[(size_t)v * NNODE + w] = acc;
}

__global__ __launch_bounds__(256) void k_softmax(float* __restrict__ P) {
    int v = blockIdx.x, tid = threadIdx.x;
    float* row = P + (size_t)v * NNODE;
    float m = 0.f;  // relu floor: post-relu values >= 0
    for (int w = tid; w < NNODE; w += 256) m = fmaxf(m, fmaxf(row[w], 0.f));
#pragma unroll
    for (int off = 32; off > 0; off >>= 1) m = fmaxf(m, __shfl_down(m, off));
    __shared__ float redm[4];
    __shared__ float reds[4];
    int wave = tid >> 6, lane = tid & 63;
    if (lane == 0) redm[wave] = m;
    __syncthreads();
    m = fmaxf(fmaxf(redm[0], redm[1]), fmaxf(redm[2], redm[3]));
    float s = 0.f;
    for (int w = tid; w < NNODE; w += 256) s += expf(fmaxf(row[w], 0.f) - m);
#pragma unroll
    for (int off = 32; off > 0; off >>= 1) s += __shfl_down(s, off);
    if (lane == 0) reds[wave] = s;
    __syncthreads();
    s = reds[0] + reds[1] + reds[2] + reds[3];
    float inv = 1.f / s;
    for (int w = tid; w < NNODE; w += 256) row[w] = expf(fmaxf(row[w], 0.f) - m) * inv;
}

// ---------------- start conv: pad t by 1, 2 -> 32 channels ----------------
__global__ __launch_bounds__(256) void k_start(const float* __restrict__ xin,
                                               const float* __restrict__ sw,
                                               const float* __restrict__ sb,
                                               float* __restrict__ out, int b0) {
    int n = blockIdx.x * 256 + threadIdx.x;
    int t = blockIdx.y;   // 0..12 (t==0 is the zero pad)
    int bl = blockIdx.z;  // 0..7
    int b = b0 + bl;
    float x0 = 0.f, x1 = 0.f;
    if (t > 0) {
        x0 = xin[((size_t)(b * 2 + 0) * NNODE + n) * 12 + (t - 1)];
        x1 = xin[((size_t)(b * 2 + 1) * NNODE + n) * 12 + (t - 1)];
    }
#pragma unroll
    for (int co = 0; co < 32; ++co) {
        float v = sw[co * 2 + 0] * x0 + sw[co * 2 + 1] * x1 + sb[co];
        out[((size_t)(bl * 32 + co) * 13 + t) * NNODE + n] = v;
    }
}

// ------- fused dilated filter/gate conv + tanh*sigmoid, 2 n's per thread -------
__global__ __launch_bounds__(256) void k_gate(const float* __restrict__ cur,
                                              float* __restrict__ xg, int T, int Tn, int d,
                                              const float* __restrict__ fw,
                                              const float* __restrict__ fb,
                                              const float* __restrict__ gw,
                                              const float* __restrict__ gb) {
    __shared__ float4 wp[1024];  // [ci*32+co] = {fw0, fw1, gw0, gw1}
    int tid = threadIdx.x;
#pragma unroll
    for (int u = 0; u < 4; ++u) {
        int idx = tid + u * 256;
        int ci = idx >> 5, co = idx & 31;
        wp[idx] = make_float4(fw[co * 64 + ci * 2], fw[co * 64 + ci * 2 + 1],
                              gw[co * 64 + ci * 2], gw[co * 64 + ci * 2 + 1]);
    }
    __syncthreads();
    int n = blockIdx.x * 512 + tid;  // handles n and n+256
    int t = blockIdx.y;
    int bl = blockIdx.z;
    float f0[32], f1[32], g0[32], g1[32];
#pragma unroll
    for (int co = 0; co < 32; ++co) { f0[co] = 0.f; f1[co] = 0.f; g0[co] = 0.f; g1[co] = 0.f; }
    for (int ci = 0; ci < 32; ++ci) {
        size_t ba = ((size_t)(bl * 32 + ci) * T + t) * NNODE + n;
        size_t bb = ((size_t)(bl * 32 + ci) * T + t + d) * NNODE + n;
        float xa0 = cur[ba], xa1 = cur[ba + 256];
        float xb0 = cur[bb], xb1 = cur[bb + 256];
#pragma unroll
        for (int co = 0; co < 32; ++co) {
            float4 w = wp[ci * 32 + co];
            f0[co] += w.x * xa0 + w.y * xb0;
            f1[co] += w.x * xa1 + w.y * xb1;
            g0[co] += w.z * xa0 + w.w * xb0;
            g1[co] += w.z * xa1 + w.w * xb1;
        }
    }
#pragma unroll
    for (int co = 0; co < 32; ++co) {
        float fbv = fb[co], gbv = gb[co];
        float a0 = tanhf(f0[co] + fbv) * (1.f / (1.f + expf(-(g0[co] + gbv))));
        float a1 = tanhf(f1[co] + fbv) * (1.f / (1.f + expf(-(g1[co] + gbv))));
        size_t o = ((size_t)(bl * 32 + co) * Tn + t) * NNODE + n;
        xg[o] = a0;
        xg[o + 256] = a1;
    }
}

// ---- skip conv, last time step only; accumulates across layers ----
__global__ __launch_bounds__(256) void k_skip(const float* __restrict__ xg,
                                              float* __restrict__ skip, int Tn,
                                              const float* __restrict__ sw,
                                              const float* __restrict__ sb, int b0, int init) {
    __shared__ float wl[256];  // 8 sc rows x 32 ci
    int tid = threadIdx.x;
    int sc0 = blockIdx.y * 8;
    wl[tid] = sw[sc0 * 32 + tid];
    __syncthreads();
    int n = blockIdx.x * 256 + tid;
    int bl = blockIdx.z;
    float acc[8];
#pragma unroll
    for (int j = 0; j < 8; ++j) acc[j] = 0.f;
    for (int ci = 0; ci < 32; ci += 4) {
        float v0 = xg[((size_t)(bl * 32 + ci + 0) * Tn + (Tn - 1)) * NNODE + n];
        float v1 = xg[((size_t)(bl * 32 + ci + 1) * Tn + (Tn - 1)) * NNODE + n];
        float v2 = xg[((size_t)(bl * 32 + ci + 2) * Tn + (Tn - 1)) * NNODE + n];
        float v3 = xg[((size_t)(bl * 32 + ci + 3) * Tn + (Tn - 1)) * NNODE + n];
#pragma unroll
        for (int j = 0; j < 8; ++j) {
            float4 w = *(const float4*)&wl[j * 32 + ci];
            acc[j] += w.x * v0 + w.y * v1 + w.z * v2 + w.w * v3;
        }
    }
    int b = b0 + bl;
#pragma unroll
    for (int j = 0; j < 8; ++j) {
        size_t o = ((size_t)(b * 256) + sc0 + j) * NNODE + n;
        float val = acc[j] + sb[sc0 + j];
        if (init) skip[o] = val;
        else skip[o] += val;
    }
}

// ---- f32 GEMM: C[M x 2048] = X[M x 2048] * S[2048 x 2048], row-major ----
// 128x128 tile, TK=16, 8x8 micro-tile. Split-column B frags (tn*4 / 64+tn*4)
// keep LDS reads at <=2-way bank aliasing (free).
__global__ __launch_bounds__(256) void k_gemm(const float* __restrict__ X,
                                              const float* __restrict__ S,
                                              float* __restrict__ C, int M) {
    __shared__ float XsT[16][132];
    __shared__ float Ss[16][128];
    const int tid = threadIdx.x;
    const int m0 = blockIdx.y * 128;
    const int n0 = blockIdx.x * 128;
    const int tn = tid & 15;
    const int tm = tid >> 4;
    float acc[8][8];
#pragma unroll
    for (int i = 0; i < 8; ++i)
#pragma unroll
        for (int j = 0; j < 8; ++j) acc[i][j] = 0.f;
    const int xs_m = tid >> 2;
    const int xs_k = (tid & 3) * 4;
    const int ss_k = tid >> 5;
    const int ss_n = (tid & 31) * 4;
    for (int k0 = 0; k0 < NNODE; k0 += 16) {
#pragma unroll
        for (int j = 0; j < 2; ++j) {
            int m = xs_m + j * 64;
            float4 v = *(const float4*)&X[(size_t)(m0 + m) * NNODE + k0 + xs_k];
            XsT[xs_k + 0][m] = v.x;
            XsT[xs_k + 1][m] = v.y;
            XsT[xs_k + 2][m] = v.z;
            XsT[xs_k + 3][m] = v.w;
        }
#pragma unroll
        for (int j = 0; j < 2; ++j) {
            int kk = ss_k + j * 8;
            *(float4*)&Ss[kk][ss_n] = *(const float4*)&S[(size_t)(k0 + kk) * NNODE + n0 + ss_n];
        }
        __syncthreads();
#pragma unroll
        for (int k = 0; k < 16; ++k) {
            float a[8], b[8];
            *(float4*)&a[0] = *(const float4*)&XsT[k][tm * 8];
            *(float4*)&a[4] = *(const float4*)&XsT[k][tm * 8 + 4];
            *(float4*)&b[0] = *(const float4*)&Ss[k][tn * 4];
            *(float4*)&b[4] = *(const float4*)&Ss[k][64 + tn * 4];
#pragma unroll
            for (int i = 0; i < 8; ++i)
#pragma unroll
                for (int j = 0; j < 8; ++j) acc[i][j] += a[i] * b[j];
        }
        __syncthreads();
    }
#pragma unroll
    for (int i = 0; i < 8; ++i) {
        size_t r = (size_t)(m0 + tm * 8 + i) * NNODE + n0;
        float4 v0 = make_float4(acc[i][0], acc[i][1], acc[i][2], acc[i][3]);
        float4 v1 = make_float4(acc[i][4], acc[i][5], acc[i][6], acc[i][7]);
        *(float4*)&C[r + tn * 4] = v0;
        *(float4*)&C[r + 64 + tn * 4] = v1;
    }
}

// ---- GCN accumulate: x_next (+)= W_g * src_g; final pass adds residual + BN ----
__global__ __launch_bounds__(256) void k_accum(const float* __restrict__ s0,
                                               const float* __restrict__ s1,
                                               const float* __restrict__ s2,
                                               int c0, int c1, int c2,
                                               const float* __restrict__ gcnw,
                                               const float* __restrict__ gcnb,
                                               float* __restrict__ out,
                                               const float* __restrict__ resid,
                                               int Tn, int d, int initf, int finalf,
                                               const float* __restrict__ bng,
                                               const float* __restrict__ bnb,
                                               const float* __restrict__ bnm,
                                               const float* __restrict__ bnv) {
    __shared__ float wl[3][32][32];  // [g][ci][co]
    int tid = threadIdx.x;
#pragma unroll
    for (int g = 0; g < 3; ++g) {
        int cg = (g == 0) ? c0 : (g == 1) ? c1 : c2;
#pragma unroll
        for (int u = 0; u < 4; ++u) {
            int idx = tid + u * 256;
            int ci = idx >> 5, co = idx & 31;
            wl[g][ci][co] = gcnw[co * 224 + cg + ci];
        }
    }
    __syncthreads();
    int n = blockIdx.x * 512 + tid;  // n and n+256
    int t = blockIdx.y, bl = blockIdx.z;
    float a0[32], a1[32];
#pragma unroll
    for (int co = 0; co < 32; ++co) { a0[co] = 0.f; a1[co] = 0.f; }
    for (int ci = 0; ci < 32; ++ci) {
        size_t off = ((size_t)(bl * 32 + ci) * Tn + t) * NNODE + n;
        if (s0) {
            float v0 = s0[off], v1 = s0[off + 256];
#pragma unroll
            for (int cq = 0; cq < 8; ++cq) {
                float4 w = *(const float4*)&wl[0][ci][cq * 4];
                a0[cq * 4 + 0] += w.x * v0; a1[cq * 4 + 0] += w.x * v1;
                a0[cq * 4 + 1] += w.y * v0; a1[cq * 4 + 1] += w.y * v1;
                a0[cq * 4 + 2] += w.z * v0; a1[cq * 4 + 2] += w.z * v1;
                a0[cq * 4 + 3] += w.w * v0; a1[cq * 4 + 3] += w.w * v1;
            }
        }
        {
            float v0 = s1[off], v1 = s1[off + 256];
#pragma unroll
            for (int cq = 0; cq < 8; ++cq) {
                float4 w = *(const float4*)&wl[1][ci][cq * 4];
                a0[cq * 4 + 0] += w.x * v0; a1[cq * 4 + 0] += w.x * v1;
                a0[cq * 4 + 1] += w.y * v0; a1[cq * 4 + 1] += w.y * v1;
                a0[cq * 4 + 2] += w.z * v0; a1[cq * 4 + 2] += w.z * v1;
                a0[cq * 4 + 3] += w.w * v0; a1[cq * 4 + 3] += w.w * v1;
            }
        }
        {
            float v0 = s2[off], v1 = s2[off + 256];
#pragma unroll
            for (int cq = 0; cq < 8; ++cq) {
                float4 w = *(const float4*)&wl[2][ci][cq * 4];
                a0[cq * 4 + 0] += w.x * v0; a1[cq * 4 + 0] += w.x * v1;
                a0[cq * 4 + 1] += w.y * v0; a1[cq * 4 + 1] += w.y * v1;
                a0[cq * 4 + 2] += w.z * v0; a1[cq * 4 + 2] += w.z * v1;
                a0[cq * 4 + 3] += w.w * v0; a1[cq * 4 + 3] += w.w * v1;
            }
        }
    }
#pragma unroll
    for (int co = 0; co < 32; ++co) {
        size_t o = ((size_t)(bl * 32 + co) * Tn + t) * NNODE + n;
        float v0 = a0[co], v1 = a1[co];
        if (initf) {
            float bb = gcnb[co];
            v0 += bb; v1 += bb;
        } else {
            v0 += out[o]; v1 += out[o + 256];
        }
        if (finalf) {
            size_t ro = ((size_t)(bl * 32 + co) * (Tn + d) + t + d) * NNODE + n;
            v0 += resid[ro]; v1 += resid[ro + 256];
            float inv = bng[co] * rsqrtf(bnv[co] + 1e-5f);
            float mu = bnm[co], be = bnb[co];
            v0 = (v0 - mu) * inv + be;
            v1 = (v1 - mu) * inv + be;
        }
        out[o] = v0; out[o + 256] = v1;
    }
}

// ---- end head: h = relu(E1 * relu(skip) + b1); out = E2 * h + b2 ----
__global__ __launch_bounds__(256) void k_end1(const float* __restrict__ skip,
                                              const float* __restrict__ w,
                                              const float* __restrict__ bias,
                                              float* __restrict__ h) {
    __shared__ float wl[2048];  // 8 e-rows x 256
    int tid = threadIdx.x;
    int e0 = blockIdx.y * 8;
#pragma unroll
    for (int u = 0; u < 8; ++u) wl[tid + u * 256] = w[e0 * 256 + tid + u * 256];
    __syncthreads();
    int n = blockIdx.x * 256 + tid;
    int b = blockIdx.z;
    float acc[8];
#pragma unroll
    for (int j = 0; j < 8; ++j) acc[j] = 0.f;
    for (int c = 0; c < 256; c += 4) {
        float v0 = fmaxf(skip[((size_t)(b * 256) + c + 0) * NNODE + n], 0.f);
        float v1 = fmaxf(skip[((size_t)(b * 256) + c + 1) * NNODE + n], 0.f);
        float v2 = fmaxf(skip[((size_t)(b * 256) + c + 2) * NNODE + n], 0.f);
        float v3 = fmaxf(skip[((size_t)(b * 256) + c + 3) * NNODE + n], 0.f);
#pragma unroll
        for (int j = 0; j < 8; ++j) {
            float4 wv = *(const float4*)&wl[j * 256 + c];
            acc[j] += wv.x * v0 + wv.y * v1 + wv.z * v2 + wv.w * v3;
        }
    }
#pragma unroll
    for (int j = 0; j < 8; ++j)
        h[((size_t)(b * 512) + e0 + j) * NNODE + n] = fmaxf(acc[j] + bias[e0 + j], 0.f);
}

__global__ __launch_bounds__(256) void k_end2(const float* __restrict__ h,
                                              const float* __restrict__ w,
                                              const float* __restrict__ bias,
                                              float* __restrict__ out) {
    __shared__ float wl[512];
    int tid = threadIdx.x;
    int o = blockIdx.y;
    wl[tid] = w[o * 512 + tid];
    wl[tid + 256] = w[o * 512 + tid + 256];
    __syncthreads();
    int n = blockIdx.x * 256 + tid;
    int b = blockIdx.z;
    float acc = 0.f;
    for (int e = 0; e < 512; ++e) acc += wl[e] * h[((size_t)(b * 512) + e) * NNODE + n];
    out[((size_t)(b * 12) + o) * NNODE + n] = acc + bias[o];
}

extern "C" void kernel_launch(void* const* d_in, const int* in_sizes, int n_in,
                              void* d_out, int out_size, void* d_ws, size_t ws_size,
                              hipStream_t stream) {
    const float* x_in = (const float*)d_in[0];
    const float* A    = (const float*)d_in[1];
    const float* nv1  = (const float*)d_in[2];
    const float* nv2  = (const float*)d_in[3];
    const float* fw   = (const float*)d_in[4];
    const float* fb   = (const float*)d_in[5];
    const float* gw   = (const float*)d_in[6];
    const float* gb   = (const float*)d_in[7];
    const float* skw  = (const float*)d_in[8];
    const float* skb  = (const float*)d_in[9];
    const float* gcw  = (const float*)d_in[10];
    const float* gcb  = (const float*)d_in[11];
    const float* bng  = (const float*)d_in[12];
    const float* bnb  = (const float*)d_in[13];
    const float* bnm  = (const float*)d_in[14];
    const float* bnv  = (const float*)d_in[15];
    const float* stw  = (const float*)d_in[16];
    const float* stb  = (const float*)d_in[17];
    const float* e1w  = (const float*)d_in[18];
    const float* e1b  = (const float*)d_in[19];
    const float* e2w  = (const float*)d_in[20];
    const float* e2b  = (const float*)d_in[21];
    (void)in_sizes; (void)n_in; (void)out_size; (void)ws_size;

    float* ws   = (float*)d_ws;
    float* adp  = ws + OFF_ADP;
    float* skip = ws + OFF_SKIP;
    float* bufA = ws + OFF_A;
    float* bufB = ws + OFF_B;
    float* xg   = ws + OFF_XG;
    float* t1   = ws + OFF_T1;
    float* t2   = ws + OFF_T2;
    float* h    = ws + OFF_XG;  // overlay, activations dead by then

    k_adp_mm<<<dim3(8, 2048), 256, 0, stream>>>(nv1, nv2, adp);
    k_softmax<<<2048, 256, 0, stream>>>(adp);

    static const int DIL[NLAYER] = {1, 2, 1, 2, 1, 2, 1, 2};
    for (int ch = 0; ch < 2; ++ch) {
        int b0 = ch * 8;
        k_start<<<dim3(8, 13, 8), 256, 0, stream>>>(x_in, stw, stb, bufA, b0);
        float* cur = bufA;
        float* nxt = bufB;
        int T = 13;
        for (int i = 0; i < NLAYER; ++i) {
            int d = DIL[i], Tn = T - d;
            k_gate<<<dim3(4, Tn, 8), 256, 0, stream>>>(cur, xg, T, Tn, d,
                fw + i * 2048, fb + i * 32, gw + i * 2048, gb + i * 32);
            k_skip<<<dim3(8, 32, 8), 256, 0, stream>>>(xg, skip, Tn,
                skw + i * 256 * 32, skb + i * 256, b0, (i == 0 && 1) ? 1 : 0);
            if (i == NLAYER - 1) break;  // layer 7's GCN output is dead (only skip survives)
            int M = 256 * Tn;
            for (int s = 0; s < 3; ++s) {
                const float* As = (s < 2) ? (A + (size_t)s * NNODE * NNODE) : adp;
                k_gemm<<<dim3(16, M / 128), 256, 0, stream>>>(xg, As, t1, M);
                k_gemm<<<dim3(16, M / 128), 256, 0, stream>>>(t1, As, t2, M);
                k_accum<<<dim3(4, Tn, 8), 256, 0, stream>>>(
                    (s == 0) ? xg : nullptr, t1, t2,
                    0, (1 + 2 * s) * 32, (2 + 2 * s) * 32,
                    gcw + i * 32 * 224, gcb + i * 32,
                    nxt, cur, Tn, d, (s == 0) ? 1 : 0, (s == 2) ? 1 : 0,
                    bng + i * 32, bnb + i * 32, bnm + i * 32, bnv + i * 32);
            }
            float* tmp = cur; cur = nxt; nxt = tmp;
            T = Tn;
        }
    }
    k_end1<<<dim3(8, 64, 16), 256, 0, stream>>>(skip, e1w, e1b, h);
    k_end2<<<dim3(8, 12, 16), 256, 0, stream>>>(h, e2w, e2b, (float*)d_out);
}

// Round 2
// 5859.011 us; speedup vs baseline: 5.2791x; 5.2791x over previous
//
#include <hip/hip_runtime.h>
#include <math.h>

// GraphWaveNet forward — Round 2: bf16 MFMA GEMMs.
//
// Layout: activations [bl][c][t][n], n=2048 innermost -> GCN hop is a row-major
// GEMM (M x 2048)*(2048 x 2048), M = 256*Tn per 8-batch chunk.
// Supports pre-transposed to bf16 S^T so both MFMA operands are k-contiguous
// in LDS (m97 "gemm_bt" structure: 128x128 tile, BK=32, global_load_lds w=16).
// Hop1 fused across 3 supports (N=6144, one dispatch); hop2 per-support.
// skip telescopes: only last time step of each layer contributes.
//
// Workspace (bytes):                                  off          size
//   S_bfT  (3 x 2048 x 2048 bf16)                     0            25,165,824
//   skip   (16 x 256 x 2048 f32)                      25,165,824   33,554,432
//   bufA   (8 x 32 x 13 x 2048 f32)                   58,720,256   27,262,976
//   bufB   (8 x 32 x 13 x 2048 f32)                   85,983,232   27,262,976
//   xg_bf  (8 x 32 x 12 x 2048 bf16)                  113,246,208  12,582,912
//   t1_bf  (3072 x 6144 bf16)                         125,829,120  37,748,736
//   t2s_bf (3072 x 2048 bf16)                         163,577,856  12,582,912
//   adp f32 overlays t1_bf; h f32 (64MB) overlays bufA..xg_bf.
// total 176,160,768 B  (< 180,355,072 proven good in round 1)

#define NNODE 2048
#define NLAYER 8

typedef unsigned short u16;
typedef __attribute__((ext_vector_type(8))) short bf16x8;
typedef __attribute__((ext_vector_type(4))) float f32x4;

__device__ __forceinline__ u16 f2bf(float f) {
    unsigned u = __builtin_bit_cast(unsigned, f);
    u += 0x7fffu + ((u >> 16) & 1u);   // round-to-nearest-even
    return (u16)(u >> 16);
}
__device__ __forceinline__ float bf2f(u16 h) {
    unsigned u = ((unsigned)h) << 16;
    return __builtin_bit_cast(float, u);
}

__device__ __forceinline__ void gld16(const void* g, void* l) {
    __builtin_amdgcn_global_load_lds(
        (const __attribute__((address_space(1))) unsigned int*)g,
        (__attribute__((address_space(3))) unsigned int*)l, 16, 0, 0);
}

// ---------------- adp = softmax(relu(nv1 @ nv2), axis=1) ----------------
__global__ __launch_bounds__(256) void k_adp_mm(const float* __restrict__ nv1,
                                                const float* __restrict__ nv2,
                                                float* __restrict__ P) {
    int v = blockIdx.y;
    int w = blockIdx.x * 256 + threadIdx.x;
    float acc = 0.f;
#pragma unroll
    for (int k = 0; k < 10; ++k) acc += nv1[v * 10 + k] * nv2[k * NNODE + w];
    P[(size_t)v * NNODE + w] = acc;
}

__global__ __launch_bounds__(256) void k_softmax(float* __restrict__ P) {
    int v = blockIdx.x, tid = threadIdx.x;
    float* row = P + (size_t)v * NNODE;
    float m = 0.f;
    for (int w = tid; w < NNODE; w += 256) m = fmaxf(m, fmaxf(row[w], 0.f));
#pragma unroll
    for (int off = 32; off > 0; off >>= 1) m = fmaxf(m, __shfl_down(m, off));
    __shared__ float redm[4];
    __shared__ float reds[4];
    int wave = tid >> 6, lane = tid & 63;
    if (lane == 0) redm[wave] = m;
    __syncthreads();
    m = fmaxf(fmaxf(redm[0], redm[1]), fmaxf(redm[2], redm[3]));
    float s = 0.f;
    for (int w = tid; w < NNODE; w += 256) s += expf(fmaxf(row[w], 0.f) - m);
#pragma unroll
    for (int off = 32; off > 0; off >>= 1) s += __shfl_down(s, off);
    if (lane == 0) reds[wave] = s;
    __syncthreads();
    s = reds[0] + reds[1] + reds[2] + reds[3];
    float inv = 1.f / s;
    for (int w = tid; w < NNODE; w += 256) row[w] = expf(fmaxf(row[w], 0.f) - m) * inv;
}

// ---- transpose supports to bf16: ST[s][w][v] = src_s[v][w] ----
__global__ __launch_bounds__(256) void k_transp(const float* __restrict__ A,
                                                const float* __restrict__ adp,
                                                u16* __restrict__ ST) {
    __shared__ float tile[32][33];
    int s = blockIdx.z;
    const float* src = (s < 2) ? (A + (size_t)s * NNODE * NNODE) : adp;
    int v0 = blockIdx.y * 32, w0 = blockIdx.x * 32;
    int tx = threadIdx.x & 31, ty = threadIdx.x >> 5;  // 32 x 8
#pragma unroll
    for (int p = 0; p < 4; ++p)
        tile[ty + p * 8][tx] = src[(size_t)(v0 + ty + p * 8) * NNODE + w0 + tx];
    __syncthreads();
    u16* dst = ST + (size_t)s * NNODE * NNODE;
#pragma unroll
    for (int p = 0; p < 4; ++p)
        dst[(size_t)(w0 + ty + p * 8) * NNODE + v0 + tx] = f2bf(tile[tx][ty + p * 8]);
}

// ---------------- start conv: pad t by 1, 2 -> 32 channels ----------------
__global__ __launch_bounds__(256) void k_start(const float* __restrict__ xin,
                                               const float* __restrict__ sw,
                                               const float* __restrict__ sb,
                                               float* __restrict__ out, int b0) {
    int n = blockIdx.x * 256 + threadIdx.x;
    int t = blockIdx.y;
    int bl = blockIdx.z;
    int b = b0 + bl;
    float x0 = 0.f, x1 = 0.f;
    if (t > 0) {
        x0 = xin[((size_t)(b * 2 + 0) * NNODE + n) * 12 + (t - 1)];
        x1 = xin[((size_t)(b * 2 + 1) * NNODE + n) * 12 + (t - 1)];
    }
#pragma unroll
    for (int co = 0; co < 32; ++co) {
        float v = sw[co * 2 + 0] * x0 + sw[co * 2 + 1] * x1 + sb[co];
        out[((size_t)(bl * 32 + co) * 13 + t) * NNODE + n] = v;
    }
}

// ------- fused dilated filter/gate conv + tanh*sigmoid -> bf16 xg -------
__global__ __launch_bounds__(256) void k_gate(const float* __restrict__ cur,
                                              u16* __restrict__ xg, int T, int Tn, int d,
                                              const float* __restrict__ fw,
                                              const float* __restrict__ fb,
                                              const float* __restrict__ gw,
                                              const float* __restrict__ gb) {
    __shared__ float4 wp[1024];  // [ci*32+co] = {fw0, fw1, gw0, gw1}
    int tid = threadIdx.x;
#pragma unroll
    for (int u = 0; u < 4; ++u) {
        int idx = tid + u * 256;
        int ci = idx >> 5, co = idx & 31;
        wp[idx] = make_float4(fw[co * 64 + ci * 2], fw[co * 64 + ci * 2 + 1],
                              gw[co * 64 + ci * 2], gw[co * 64 + ci * 2 + 1]);
    }
    __syncthreads();
    int n = blockIdx.x * 512 + tid;
    int t = blockIdx.y;
    int bl = blockIdx.z;
    float f0[32], f1[32], g0[32], g1[32];
#pragma unroll
    for (int co = 0; co < 32; ++co) { f0[co] = 0.f; f1[co] = 0.f; g0[co] = 0.f; g1[co] = 0.f; }
    for (int ci = 0; ci < 32; ++ci) {
        size_t ba = ((size_t)(bl * 32 + ci) * T + t) * NNODE + n;
        size_t bb = ((size_t)(bl * 32 + ci) * T + t + d) * NNODE + n;
        float xa0 = cur[ba], xa1 = cur[ba + 256];
        float xb0 = cur[bb], xb1 = cur[bb + 256];
#pragma unroll
        for (int co = 0; co < 32; ++co) {
            float4 w = wp[ci * 32 + co];
            f0[co] += w.x * xa0 + w.y * xb0;
            f1[co] += w.x * xa1 + w.y * xb1;
            g0[co] += w.z * xa0 + w.w * xb0;
            g1[co] += w.z * xa1 + w.w * xb1;
        }
    }
#pragma unroll
    for (int co = 0; co < 32; ++co) {
        float fbv = fb[co], gbv = gb[co];
        float a0 = tanhf(f0[co] + fbv) * (1.f / (1.f + expf(-(g0[co] + gbv))));
        float a1 = tanhf(f1[co] + fbv) * (1.f / (1.f + expf(-(g1[co] + gbv))));
        size_t o = ((size_t)(bl * 32 + co) * Tn + t) * NNODE + n;
        xg[o] = f2bf(a0);
        xg[o + 256] = f2bf(a1);
    }
}

// ---- skip conv, last time step only; accumulates across layers (f32) ----
__global__ __launch_bounds__(256) void k_skip(const u16* __restrict__ xg,
                                              float* __restrict__ skip, int Tn,
                                              const float* __restrict__ sw,
                                              const float* __restrict__ sb, int b0, int init) {
    __shared__ float wl[256];  // 8 sc rows x 32 ci
    int tid = threadIdx.x;
    int sc0 = blockIdx.y * 8;
    wl[tid] = sw[sc0 * 32 + tid];
    __syncthreads();
    int n = blockIdx.x * 256 + tid;
    int bl = blockIdx.z;
    float acc[8];
#pragma unroll
    for (int j = 0; j < 8; ++j) acc[j] = 0.f;
    for (int ci = 0; ci < 32; ci += 4) {
        float v0 = bf2f(xg[((size_t)(bl * 32 + ci + 0) * Tn + (Tn - 1)) * NNODE + n]);
        float v1 = bf2f(xg[((size_t)(bl * 32 + ci + 1) * Tn + (Tn - 1)) * NNODE + n]);
        float v2 = bf2f(xg[((size_t)(bl * 32 + ci + 2) * Tn + (Tn - 1)) * NNODE + n]);
        float v3 = bf2f(xg[((size_t)(bl * 32 + ci + 3) * Tn + (Tn - 1)) * NNODE + n]);
#pragma unroll
        for (int j = 0; j < 8; ++j) {
            float4 w = *(const float4*)&wl[j * 32 + ci];
            acc[j] += w.x * v0 + w.y * v1 + w.z * v2 + w.w * v3;
        }
    }
    int b = b0 + bl;
#pragma unroll
    for (int j = 0; j < 8; ++j) {
        size_t o = ((size_t)(b * 256) + sc0 + j) * NNODE + n;
        float val = acc[j] + sb[sc0 + j];
        if (init) skip[o] = val;
        else skip[o] += val;
    }
}

// ---- bf16 MFMA GEMM: C[M x ncols] = A[M x 2048] * S_s[2048 x 2048] ----
// A row-major bf16 (lda), B given TRANSPOSED (S^T rows, ld 2048), C bf16 (ldc).
// 128x128 tile, BK=32, 4 waves each computing 64x64 via 4x4 mfma_16x16x32.
// Support s = sbase + blockIdx.z selects offsets asstr/bsstr/csstr.
__global__ __launch_bounds__(256) void k_gemm_mfma(
    const u16* __restrict__ A, int lda, size_t asstr,
    const u16* __restrict__ BT, size_t bsstr,
    u16* __restrict__ C, int ldc, size_t csstr, int sbase) {
    __shared__ u16 Asl[128 * 32];
    __shared__ u16 Bsl[128 * 32];
    const int tid = threadIdx.x;
    const int wave = tid >> 6, lane = tid & 63;
    const int sidx = sbase + blockIdx.z;
    const u16* Ab = A + sidx * asstr + (size_t)blockIdx.y * 128 * lda;
    const u16* Bb = BT + sidx * bsstr + (size_t)blockIdx.x * 128 * NNODE;
    const int tr = tid >> 2;        // staging row 0..63
    const int tc = (tid & 3) * 8;   // staging col (bf16 units)
    char* AslB = (char*)Asl + wave * 1024;  // HW adds lane*16
    char* BslB = (char*)Bsl + wave * 1024;
    const int wm = (wave & 1) * 64, wn = (wave >> 1) * 64;
    const int fr = lane & 15;
    const int fk = (lane >> 4) * 8;
    f32x4 acc[4][4];
#pragma unroll
    for (int i = 0; i < 4; ++i)
#pragma unroll
        for (int j = 0; j < 4; ++j) acc[i][j] = (f32x4){0.f, 0.f, 0.f, 0.f};

    for (int k0 = 0; k0 < 2048; k0 += 32) {
        gld16(Ab + (size_t)tr * lda + k0 + tc, AslB);
        gld16(Ab + (size_t)(tr + 64) * lda + k0 + tc, AslB + 4096);
        gld16(Bb + (size_t)tr * NNODE + k0 + tc, BslB);
        gld16(Bb + (size_t)(tr + 64) * NNODE + k0 + tc, BslB + 4096);
        __syncthreads();
        bf16x8 af[4], bf[4];
#pragma unroll
        for (int i = 0; i < 4; ++i)
            af[i] = *(const bf16x8*)&Asl[(wm + i * 16 + fr) * 32 + fk];
#pragma unroll
        for (int j = 0; j < 4; ++j)
            bf[j] = *(const bf16x8*)&Bsl[(wn + j * 16 + fr) * 32 + fk];
#pragma unroll
        for (int i = 0; i < 4; ++i)
#pragma unroll
            for (int j = 0; j < 4; ++j)
                acc[i][j] = __builtin_amdgcn_mfma_f32_16x16x32_bf16(af[i], bf[j], acc[i][j], 0, 0, 0);
        __syncthreads();
    }
    u16* Cb = C + sidx * csstr + (size_t)(blockIdx.y * 128 + wm) * ldc + blockIdx.x * 128 + wn;
    const int orow = (lane >> 4) * 4;  // C/D: col=lane&15, row=(lane>>4)*4+r
#pragma unroll
    for (int i = 0; i < 4; ++i)
#pragma unroll
        for (int j = 0; j < 4; ++j)
#pragma unroll
            for (int r = 0; r < 4; ++r)
                Cb[(size_t)(i * 16 + orow + r) * ldc + j * 16 + fr] = f2bf(acc[i][j][r]);
}

// ---- GCN accumulate (per support): nxt (+)= W*[s0; s1; s2]; final adds resid+BN ----
__global__ __launch_bounds__(256) void k_accum(const u16* __restrict__ s0,
                                               const u16* __restrict__ s1, int ld1,
                                               const u16* __restrict__ s2, int ld2,
                                               int c0, int c1, int c2,
                                               const float* __restrict__ gcnw,
                                               const float* __restrict__ gcnb,
                                               float* __restrict__ out,
                                               const float* __restrict__ resid,
                                               int Tn, int d, int initf, int finalf,
                                               const float* __restrict__ bng,
                                               const float* __restrict__ bnb,
                                               const float* __restrict__ bnm,
                                               const float* __restrict__ bnv) {
    __shared__ float wl[3][32][32];  // [g][ci][co]
    int tid = threadIdx.x;
#pragma unroll
    for (int g = 0; g < 3; ++g) {
        int cg = (g == 0) ? c0 : (g == 1) ? c1 : c2;
#pragma unroll
        for (int u = 0; u < 4; ++u) {
            int idx = tid + u * 256;
            int ci = idx >> 5, co = idx & 31;
            wl[g][ci][co] = gcnw[co * 224 + cg + ci];
        }
    }
    __syncthreads();
    int n = blockIdx.x * 512 + tid;  // n and n+256
    int t = blockIdx.y, bl = blockIdx.z;
    float a0[32], a1[32];
#pragma unroll
    for (int co = 0; co < 32; ++co) { a0[co] = 0.f; a1[co] = 0.f; }
    for (int ci = 0; ci < 32; ++ci) {
        size_t m = (size_t)(bl * 32 + ci) * Tn + t;
        if (s0) {
            float v0 = bf2f(s0[m * NNODE + n]), v1 = bf2f(s0[m * NNODE + n + 256]);
#pragma unroll
            for (int cq = 0; cq < 8; ++cq) {
                float4 w = *(const float4*)&wl[0][ci][cq * 4];
                a0[cq * 4 + 0] += w.x * v0; a1[cq * 4 + 0] += w.x * v1;
                a0[cq * 4 + 1] += w.y * v0; a1[cq * 4 + 1] += w.y * v1;
                a0[cq * 4 + 2] += w.z * v0; a1[cq * 4 + 2] += w.z * v1;
                a0[cq * 4 + 3] += w.w * v0; a1[cq * 4 + 3] += w.w * v1;
            }
        }
        {
            float v0 = bf2f(s1[m * ld1 + n]), v1 = bf2f(s1[m * ld1 + n + 256]);
#pragma unroll
            for (int cq = 0; cq < 8; ++cq) {
                float4 w = *(const float4*)&wl[1][ci][cq * 4];
                a0[cq * 4 + 0] += w.x * v0; a1[cq * 4 + 0] += w.x * v1;
                a0[cq * 4 + 1] += w.y * v0; a1[cq * 4 + 1] += w.y * v1;
                a0[cq * 4 + 2] += w.z * v0; a1[cq * 4 + 2] += w.z * v1;
                a0[cq * 4 + 3] += w.w * v0; a1[cq * 4 + 3] += w.w * v1;
            }
        }
        {
            float v0 = bf2f(s2[m * ld2 + n]), v1 = bf2f(s2[m * ld2 + n + 256]);
#pragma unroll
            for (int cq = 0; cq < 8; ++cq) {
                float4 w = *(const float4*)&wl[2][ci][cq * 4];
                a0[cq * 4 + 0] += w.x * v0; a1[cq * 4 + 0] += w.x * v1;
                a0[cq * 4 + 1] += w.y * v0; a1[cq * 4 + 1] += w.y * v1;
                a0[cq * 4 + 2] += w.z * v0; a1[cq * 4 + 2] += w.z * v1;
                a0[cq * 4 + 3] += w.w * v0; a1[cq * 4 + 3] += w.w * v1;
            }
        }
    }
#pragma unroll
    for (int co = 0; co < 32; ++co) {
        size_t o = ((size_t)(bl * 32 + co) * Tn + t) * NNODE + n;
        float v0 = a0[co], v1 = a1[co];
        if (initf) {
            float bb = gcnb[co];
            v0 += bb; v1 += bb;
        } else {
            v0 += out[o]; v1 += out[o + 256];
        }
        if (finalf) {
            size_t ro = ((size_t)(bl * 32 + co) * (Tn + d) + t + d) * NNODE + n;
            v0 += resid[ro]; v1 += resid[ro + 256];
            float inv = bng[co] * rsqrtf(bnv[co] + 1e-5f);
            float mu = bnm[co], be = bnb[co];
            v0 = (v0 - mu) * inv + be;
            v1 = (v1 - mu) * inv + be;
        }
        out[o] = v0; out[o + 256] = v1;
    }
}

// ---- end head: h = relu(E1 * relu(skip) + b1); out = E2 * h + b2 ----
__global__ __launch_bounds__(256) void k_end1(const float* __restrict__ skip,
                                              const float* __restrict__ w,
                                              const float* __restrict__ bias,
                                              float* __restrict__ h) {
    __shared__ float wl[2048];  // 8 e-rows x 256
    int tid = threadIdx.x;
    int e0 = blockIdx.y * 8;
#pragma unroll
    for (int u = 0; u < 8; ++u) wl[tid + u * 256] = w[e0 * 256 + tid + u * 256];
    __syncthreads();
    int n = blockIdx.x * 256 + tid;
    int b = blockIdx.z;
    float acc[8];
#pragma unroll
    for (int j = 0; j < 8; ++j) acc[j] = 0.f;
    for (int c = 0; c < 256; c += 4) {
        float v0 = fmaxf(skip[((size_t)(b * 256) + c + 0) * NNODE + n], 0.f);
        float v1 = fmaxf(skip[((size_t)(b * 256) + c + 1) * NNODE + n], 0.f);
        float v2 = fmaxf(skip[((size_t)(b * 256) + c + 2) * NNODE + n], 0.f);
        float v3 = fmaxf(skip[((size_t)(b * 256) + c + 3) * NNODE + n], 0.f);
#pragma unroll
        for (int j = 0; j < 8; ++j) {
            float4 wv = *(const float4*)&wl[j * 256 + c];
            acc[j] += wv.x * v0 + wv.y * v1 + wv.z * v2 + wv.w * v3;
        }
    }
#pragma unroll
    for (int j = 0; j < 8; ++j)
        h[((size_t)(b * 512) + e0 + j) * NNODE + n] = fmaxf(acc[j] + bias[e0 + j], 0.f);
}

__global__ __launch_bounds__(256) void k_end2(const float* __restrict__ h,
                                              const float* __restrict__ w,
                                              const float* __restrict__ bias,
                                              float* __restrict__ out) {
    __shared__ float wl[512];
    int tid = threadIdx.x;
    int o = blockIdx.y;
    wl[tid] = w[o * 512 + tid];
    wl[tid + 256] = w[o * 512 + tid + 256];
    __syncthreads();
    int n = blockIdx.x * 256 + tid;
    int b = blockIdx.z;
    float acc = 0.f;
    for (int e = 0; e < 512; ++e) acc += wl[e] * h[((size_t)(b * 512) + e) * NNODE + n];
    out[((size_t)(b * 12) + o) * NNODE + n] = acc + bias[o];
}

extern "C" void kernel_launch(void* const* d_in, const int* in_sizes, int n_in,
                              void* d_out, int out_size, void* d_ws, size_t ws_size,
                              hipStream_t stream) {
    const float* x_in = (const float*)d_in[0];
    const float* A    = (const float*)d_in[1];
    const float* nv1  = (const float*)d_in[2];
    const float* nv2  = (const float*)d_in[3];
    const float* fw   = (const float*)d_in[4];
    const float* fb   = (const float*)d_in[5];
    const float* gw   = (const float*)d_in[6];
    const float* gb   = (const float*)d_in[7];
    const float* skw  = (const float*)d_in[8];
    const float* skb  = (const float*)d_in[9];
    const float* gcw  = (const float*)d_in[10];
    const float* gcb  = (const float*)d_in[11];
    const float* bng  = (const float*)d_in[12];
    const float* bnb  = (const float*)d_in[13];
    const float* bnm  = (const float*)d_in[14];
    const float* bnv  = (const float*)d_in[15];
    const float* stw  = (const float*)d_in[16];
    const float* stb  = (const float*)d_in[17];
    const float* e1w  = (const float*)d_in[18];
    const float* e1b  = (const float*)d_in[19];
    const float* e2w  = (const float*)d_in[20];
    const float* e2b  = (const float*)d_in[21];
    (void)in_sizes; (void)n_in; (void)out_size; (void)ws_size;

    char* base = (char*)d_ws;
    u16*   SbfT = (u16*)(base);
    float* skip = (float*)(base + 25165824);
    float* bufA = (float*)(base + 58720256);
    float* bufB = (float*)(base + 85983232);
    u16*   xg   = (u16*)(base + 113246208);
    u16*   t1   = (u16*)(base + 125829120);
    u16*   t2s  = (u16*)(base + 163577856);
    float* adp  = (float*)(base + 125829120);  // overlay on t1 (pre-loop only)
    float* h    = (float*)(base + 58720256);   // overlay bufA..xg (post-loop only)

    k_adp_mm<<<dim3(8, 2048), 256, 0, stream>>>(nv1, nv2, adp);
    k_softmax<<<2048, 256, 0, stream>>>(adp);
    k_transp<<<dim3(64, 64, 3), 256, 0, stream>>>(A, adp, SbfT);

    const size_t SSTR = (size_t)NNODE * NNODE;  // support stride in S_bfT
    static const int DIL[NLAYER] = {1, 2, 1, 2, 1, 2, 1, 2};
    for (int ch = 0; ch < 2; ++ch) {
        int b0 = ch * 8;
        k_start<<<dim3(8, 13, 8), 256, 0, stream>>>(x_in, stw, stb, bufA, b0);
        float* cur = bufA;
        float* nxt = bufB;
        int T = 13;
        for (int i = 0; i < NLAYER; ++i) {
            int d = DIL[i], Tn = T - d;
            k_gate<<<dim3(4, Tn, 8), 256, 0, stream>>>(cur, xg, T, Tn, d,
                fw + i * 2048, fb + i * 32, gw + i * 2048, gb + i * 32);
            k_skip<<<dim3(8, 32, 8), 256, 0, stream>>>(xg, skip, Tn,
                skw + i * 256 * 32, skb + i * 256, b0, (i == 0) ? 1 : 0);
            if (i == NLAYER - 1) break;  // layer 7's GCN output is dead
            int MB = 2 * Tn;  // (256*Tn)/128
            // hop1 fused over 3 supports: t1[:, s*2048 + :] = xg @ S_s
            k_gemm_mfma<<<dim3(16, MB, 3), 256, 0, stream>>>(
                xg, NNODE, (size_t)0, SbfT, SSTR, t1, 3 * NNODE, (size_t)NNODE, 0);
            for (int s = 0; s < 3; ++s) {
                // hop2: t2s = t1_s @ S_s
                k_gemm_mfma<<<dim3(16, MB, 1), 256, 0, stream>>>(
                    t1, 3 * NNODE, (size_t)NNODE, SbfT, SSTR, t2s, NNODE, (size_t)0, s);
                k_accum<<<dim3(4, Tn, 8), 256, 0, stream>>>(
                    (s == 0) ? xg : (const u16*)nullptr,
                    t1 + s * NNODE, 3 * NNODE, t2s, NNODE,
                    0, (1 + 2 * s) * 32, (2 + 2 * s) * 32,
                    gcw + i * 32 * 224, gcb + i * 32,
                    nxt, cur, Tn, d, (s == 0) ? 1 : 0, (s == 2) ? 1 : 0,
                    bng + i * 32, bnb + i * 32, bnm + i * 32, bnv + i * 32);
            }
            float* tmp = cur; cur = nxt; nxt = tmp;
            T = Tn;
        }
    }
    k_end1<<<dim3(8, 64, 16), 256, 0, stream>>>(skip, e1w, e1b, h);
    k_end2<<<dim3(8, 12, 16), 256, 0, stream>>>(h, e2w, e2b, (float*)d_out);
}